// Round 1
// baseline (95.586 us; speedup 1.0000x reference)
//
#include <hip/hip_runtime.h>

// Problem constants fixed by setup_inputs() in the reference file.
constexpr int H          = 768;
constexpr int HV         = H / 4;                 // 192 float4 per row
constexpr int MAX_TOKEN  = 65536;
constexpr int MAX_SENT   = 4096;
constexpr int SENT_START = MAX_TOKEN;             // 65536
constexpr int MAX_PARA   = 128;
constexpr int PARA_START = SENT_START + MAX_SENT; // 69632
constexpr int N_TOTAL    = MAX_TOKEN + MAX_SENT + MAX_PARA + 1; // 69761
constexpr int TOK_PER_SENT = MAX_TOKEN / MAX_SENT;   // 16
constexpr int INDOC      = 512;                   // max_indoc_token

// Fused: copy token rows to out AND compute the sentence means in one pass,
// so hidden_states is read exactly once from HBM.
// Block = one sentence (16 contiguous token rows); 192 threads, one float4
// column chunk per thread. Block reads/writes a contiguous 48 KB span.
__global__ __launch_bounds__(192) void fuse_tok_sent(
    const float* __restrict__ hid, float* __restrict__ out) {
    const int s = blockIdx.x;       // sentence id [0, MAX_SENT)
    const int c = threadIdx.x;      // float4 column [0, HV)

    const float4* __restrict__ src =
        reinterpret_cast<const float4*>(hid) + (size_t)s * TOK_PER_SENT * HV + c;
    float4* __restrict__ dst =
        reinterpret_cast<float4*>(out) + (size_t)s * TOK_PER_SENT * HV + c;

    float4 acc = make_float4(0.f, 0.f, 0.f, 0.f);
#pragma unroll
    for (int r = 0; r < TOK_PER_SENT; ++r) {
        float4 v = src[(size_t)r * HV];
        dst[(size_t)r * HV] = v;
        acc.x += v.x; acc.y += v.y; acc.z += v.z; acc.w += v.w;
    }
    const float inv = 1.0f / (float)TOK_PER_SENT;
    acc.x *= inv; acc.y *= inv; acc.z *= inv; acc.w *= inv;
    reinterpret_cast<float4*>(out)[(size_t)(SENT_START + s) * HV + c] = acc;
}

// Paragraph rows = token rows at stride INDOC (128 of them);
// document row = mean of those 128 rows.
__global__ __launch_bounds__(192) void para_doc(
    const float* __restrict__ hid, float* __restrict__ out) {
    const int p = blockIdx.x;   // [0, MAX_PARA] ; last block does the doc node
    const int c = threadIdx.x;  // float4 column

    const float4* __restrict__ hv = reinterpret_cast<const float4*>(hid);
    float4* __restrict__ ov = reinterpret_cast<float4*>(out);

    if (p < MAX_PARA) {
        float4 v = hv[(size_t)p * INDOC * HV + c];
        ov[(size_t)(PARA_START + p) * HV + c] = v;
    } else {
        float4 acc = make_float4(0.f, 0.f, 0.f, 0.f);
#pragma unroll 4
        for (int q = 0; q < MAX_PARA; ++q) {
            float4 v = hv[(size_t)q * INDOC * HV + c];
            acc.x += v.x; acc.y += v.y; acc.z += v.z; acc.w += v.w;
        }
        const float inv = 1.0f / (float)MAX_PARA;
        acc.x *= inv; acc.y *= inv; acc.z *= inv; acc.w *= inv;
        ov[(size_t)(N_TOTAL - 1) * HV + c] = acc;
    }
}

extern "C" void kernel_launch(void* const* d_in, const int* in_sizes, int n_in,
                              void* d_out, int out_size, void* d_ws, size_t ws_size,
                              hipStream_t stream) {
    const float* hid = (const float*)d_in[0];   // hidden_states [65536, 768] fp32
    float* out = (float*)d_out;                 // [1, 69761, 768] fp32

    hipLaunchKernelGGL(fuse_tok_sent, dim3(MAX_SENT), dim3(192), 0, stream, hid, out);
    hipLaunchKernelGGL(para_doc, dim3(MAX_PARA + 1), dim3(192), 0, stream, hid, out);
}

// Round 3
// 65.512 us; speedup vs baseline: 1.4590x; 1.4590x over previous
//
#include <hip/hip_runtime.h>

// Problem constants fixed by setup_inputs() in the reference file.
constexpr int H          = 768;
constexpr int HV         = H / 4;                 // 192 float4 per row
constexpr int MAX_TOKEN  = 65536;
constexpr int MAX_SENT   = 4096;
constexpr int SENT_START = MAX_TOKEN;             // 65536
constexpr int MAX_PARA   = 128;
constexpr int PARA_START = SENT_START + MAX_SENT; // 69632
constexpr int N_TOTAL    = MAX_TOKEN + MAX_SENT + MAX_PARA + 1; // 69761
constexpr int TOK_PER_SENT = MAX_TOKEN / MAX_SENT;   // 16
constexpr int INDOC      = 512;                   // max_indoc_token

// Native clang vector type — __builtin_nontemporal_store requires this
// (HIP's float4 is a class and is rejected).
typedef float fx4 __attribute__((ext_vector_type(4)));

__device__ __forceinline__ void nt_store(fx4* p, fx4 v) {
    __builtin_nontemporal_store(v, p);
}

// One kernel, one grid:
//   blocks [0, 4096)        : sentence s — copy its 16 token rows to out and
//                             write the row mean to the sentence node.
//   blocks [4096, 4224)     : paragraph p — copy token row 512*p.
//   block  4224             : document node — mean of the 128 paragraph rows.
// 192 threads = one float4 column chunk each; every global access is a
// contiguous 1 KiB/wave transaction. All stores are non-temporal: the output
// is never re-read by the kernel, so keep it out of L2/L3 and let
// hidden_states (201 MB) stay resident in the 256 MB Infinity Cache.
__global__ __launch_bounds__(192) void fused_all(
    const float* __restrict__ hid, float* __restrict__ out) {
    const int b = blockIdx.x;
    const int c = threadIdx.x;      // float4 column [0, HV)

    const fx4* __restrict__ hv = reinterpret_cast<const fx4*>(hid);
    fx4* __restrict__ ov = reinterpret_cast<fx4*>(out);

    if (b < MAX_SENT) {
        const int s = b;
        const fx4* __restrict__ src = hv + (size_t)s * TOK_PER_SENT * HV + c;
        fx4* __restrict__ dst = ov + (size_t)s * TOK_PER_SENT * HV + c;

        fx4 acc = (fx4)0.0f;
#pragma unroll
        for (int r = 0; r < TOK_PER_SENT; ++r) {
            fx4 v = src[(size_t)r * HV];
            nt_store(&dst[(size_t)r * HV], v);
            acc += v;
        }
        acc *= (1.0f / (float)TOK_PER_SENT);
        nt_store(&ov[(size_t)(SENT_START + s) * HV + c], acc);
    } else if (b < MAX_SENT + MAX_PARA) {
        const int p = b - MAX_SENT;
        fx4 v = hv[(size_t)p * INDOC * HV + c];
        nt_store(&ov[(size_t)(PARA_START + p) * HV + c], v);
    } else {
        fx4 acc = (fx4)0.0f;
#pragma unroll 4
        for (int q = 0; q < MAX_PARA; ++q) {
            acc += hv[(size_t)q * INDOC * HV + c];
        }
        acc *= (1.0f / (float)MAX_PARA);
        nt_store(&ov[(size_t)(N_TOTAL - 1) * HV + c], acc);
    }
}

extern "C" void kernel_launch(void* const* d_in, const int* in_sizes, int n_in,
                              void* d_out, int out_size, void* d_ws, size_t ws_size,
                              hipStream_t stream) {
    const float* hid = (const float*)d_in[0];   // hidden_states [65536, 768] fp32
    float* out = (float*)d_out;                 // [1, 69761, 768] fp32

    hipLaunchKernelGGL(fused_all, dim3(MAX_SENT + MAX_PARA + 1), dim3(192), 0,
                       stream, hid, out);
}